// Round 7
// baseline (261.605 us; speedup 1.0000x reference)
//
#include <hip/hip_runtime.h>
#include <math.h>

#define S_DIM 512
#define B_DIM 128
#define H_DIM 512
#define T_DIM 48

typedef short bf16x8 __attribute__((ext_vector_type(8)));   // 8 bf16 = 4 VGPR (MFMA A/B frag)
typedef short s16x4  __attribute__((ext_vector_type(4)));
typedef float f32x4  __attribute__((ext_vector_type(4)));   // MFMA C/D frag

__device__ __forceinline__ short rne_bf(float f) {  // fp32 -> bf16 round-nearest-even
  unsigned u = __float_as_uint(f);
  u += 0x7fffu + ((u >> 16) & 1u);
  return (short)(u >> 16);
}
__device__ __forceinline__ short trunc_bf(float f) {  // cheap truncation (hot path)
  return (short)(__float_as_uint(f) >> 16);
}
__device__ __forceinline__ bf16x8 cvt8(const float* __restrict__ p) {  // 8 fp32 -> bf16x8
  float4 v0 = *(const float4*)p, v1 = *(const float4*)(p + 4);
  bf16x8 r;
  r[0] = rne_bf(v0.x); r[1] = rne_bf(v0.y); r[2] = rne_bf(v0.z); r[3] = rne_bf(v0.w);
  r[4] = rne_bf(v1.x); r[5] = rne_bf(v1.y); r[6] = rne_bf(v1.z); r[7] = rne_bf(v1.w);
  return r;
}

// ---------------------------------------------------------------------------
// Node format: 48x48 bf16, COLUMN-major: node[j*48 + k] = M[k][j].
// B-frag source: lane reads 8 consecutive k at fixed column j = 16ct+q.
// ---------------------------------------------------------------------------
struct Frags6 { bf16x8 b[2][3]; };  // [kstep][coltile]

__device__ __forceinline__ void load_child(const short* __restrict__ p, int h, int q, Frags6& f) {
  bf16x8 z = 0;
#pragma unroll
  for (int ct = 0; ct < 3; ++ct) {
    const short* col = p + (16 * ct + q) * 48;
    f.b[0][ct] = *(const bf16x8*)(col + 8 * h);                       // k = 8h..8h+7 (<32)
    f.b[1][ct] = (h < 2) ? *(const bf16x8*)(col + 32 + 8 * h) : z;    // k = 32..47, pad 0
  }
}

// one product step: C = A x B, A = (useI ? I48 : M in LDS), 18 MFMA, C fully overwritten
// Ml: [48 rows][64 k] bf16, short idx = row*64 + (k ^ ((row&7)<<3))  (XOR swizzle)
__device__ __forceinline__ void matstep(const short* Ml, bool useI, int h, int q,
                                        const Frags6& B, f32x4 C[3][3]) {
  const f32x4 Z = {0.f, 0.f, 0.f, 0.f};
#pragma unroll
  for (int rt = 0; rt < 3; ++rt) {
    const int row = 16 * rt + q;
    bf16x8 a0, a1;
    if (useI) {
      const short one = (short)0x3F80;  // bf16 1.0
#pragma unroll
      for (int i = 0; i < 8; ++i) {
        a0[i] = (row == 8 * h + i) ? one : (short)0;
        a1[i] = (row == 32 + 8 * h + i) ? one : (short)0;
      }
    } else {
      const int sw = (row & 7) << 3;
      a0 = *(const bf16x8*)&Ml[row * 64 + ((8 * h) ^ sw)];
      a1 = *(const bf16x8*)&Ml[row * 64 + ((32 + 8 * h) ^ sw)];
    }
#pragma unroll
    for (int ct = 0; ct < 3; ++ct)
      C[rt][ct] = __builtin_amdgcn_mfma_f32_16x16x32_bf16(
          a1, B.b[1][ct],
          __builtin_amdgcn_mfma_f32_16x16x32_bf16(a0, B.b[0][ct], Z, 0, 0, 0), 0, 0, 0);
  }
}

// write C (fp32) back into M LDS as bf16.  D-frag: row = 16rt+4h+r, col = 16ct+q.
__device__ __forceinline__ void writeM(short* Ml, int h, int q, const f32x4 C[3][3]) {
#pragma unroll
  for (int rt = 0; rt < 3; ++rt)
#pragma unroll
    for (int ct = 0; ct < 3; ++ct) {
      const int j = 16 * ct + q;
#pragma unroll
      for (int r = 0; r < 4; ++r) {
        const int row = 16 * rt + 4 * h + r;
        Ml[row * 64 + (j ^ ((row & 7) << 3))] = trunc_bf(C[rt][ct][r]);
      }
    }
}

// store C to a col-major node (values assumed already in range)
__device__ __forceinline__ void storecol(short* __restrict__ node, int h, int q,
                                         const f32x4 C[3][3]) {
#pragma unroll
  for (int rt = 0; rt < 3; ++rt)
#pragma unroll
    for (int ct = 0; ct < 3; ++ct) {
      s16x4 pk;
#pragma unroll
      for (int r = 0; r < 4; ++r) pk[r] = rne_bf(C[rt][ct][r]);
      *(s16x4*)&node[(16 * ct + q) * 48 + 16 * rt + 4 * h] = pk;
    }
}

// wave-wide rescale of C so max in [0.5,1); exact power of 2, returns exponent
__device__ __forceinline__ int rescaleC(f32x4 C[3][3]) {
  float mx = 0.f;
#pragma unroll
  for (int rt = 0; rt < 3; ++rt)
#pragma unroll
    for (int ct = 0; ct < 3; ++ct)
#pragma unroll
      for (int r = 0; r < 4; ++r) mx = fmaxf(mx, C[rt][ct][r]);
#pragma unroll
  for (int off = 1; off < 64; off <<= 1) mx = fmaxf(mx, __shfl_xor(mx, off, 64));
  int ex;
  frexpf(mx, &ex);
  const float sc = ldexpf(1.0f, -ex);
#pragma unroll
  for (int rt = 0; rt < 3; ++rt)
#pragma unroll
    for (int ct = 0; ct < 3; ++ct)
#pragma unroll
      for (int r = 0; r < 4; ++r) C[rt][ct][r] *= sc;
  return ex;
}

// rescale + store col-major node; returns exponent
__device__ __forceinline__ int store_node(short* __restrict__ node, int h, int q,
                                          f32x4 C[3][3]) {
  int ex = rescaleC(C);
  storecol(node, h, q, C);
  return ex;
}

__device__ __forceinline__ void zero_lds(short* Ml, int l) {
  s16x4 z = 0;
#pragma unroll
  for (int i = 0; i < 12; ++i) *(s16x4*)&Ml[(l + 64 * i) * 4] = z;  // 48*64 shorts
}

// ---------------------------------------------------------------------------
// K1 (fused): block (b,c) computes em rows s in [16c, 16c+15] via MFMA from
// wf/W (phase 1, em kept in regs AND written to global for k_final), then runs
// the chain N_c = prod A_s over s in [max(1,16c), 16c+15] using 3 shuffles per
// step to fetch e-values from the em regs (phase 2).
// 128*32 blocks x 64 thr (1 wave).  Also zeroes out[0].
// ---------------------------------------------------------------------------
__global__ __launch_bounds__(64) void k_fused(
    const float* __restrict__ wf, const float* __restrict__ W,
    const float* __restrict__ bias, const float* __restrict__ trans,
    float* __restrict__ em, short* __restrict__ nodes1, int* __restrict__ exp1,
    float* __restrict__ out) {
  const int b = blockIdx.x >> 5, c = blockIdx.x & 31;
  const int l = threadIdx.x, h = l >> 4, q = l & 15;
  if (blockIdx.x == 0 && l == 0) out[0] = 0.0f;

  // ---- phase 1: em rows s0..s0+15, s0 = 16c.  A row = q (s = s0+q). ----
  const int s0 = 16 * c;
  f32x4 E[3];
#pragma unroll
  for (int ct = 0; ct < 3; ++ct) E[ct] = 0.f;

  for (int ks = 0; ks < 16; ++ks) {
    const int k0 = 32 * ks + 8 * h;
    bf16x8 a = cvt8(&wf[((size_t)(s0 + q) * B_DIM + b) * H_DIM + k0]);
    bf16x8 bb[3];
#pragma unroll
    for (int ct = 0; ct < 3; ++ct)
      bb[ct] = cvt8(&W[(size_t)(16 * ct + q) * H_DIM + k0]);
#pragma unroll
    for (int ct = 0; ct < 3; ++ct)
      E[ct] = __builtin_amdgcn_mfma_f32_16x16x32_bf16(a, bb[ct], E[ct], 0, 0, 0);
  }
#pragma unroll
  for (int ct = 0; ct < 3; ++ct) {
    const float bv = bias[16 * ct + q];
#pragma unroll
    for (int r = 0; r < 4; ++r) E[ct][r] += bv;
  }
  // write em to global (k_final needs gold gather + u0 row).  D row = 4h+r.
#pragma unroll
  for (int r = 0; r < 4; ++r) {
    const size_t ro = ((size_t)(s0 + 4 * h + r) * B_DIM + b) * T_DIM;
#pragma unroll
    for (int ct = 0; ct < 3; ++ct) em[ro + 16 * ct + q] = E[ct][r];
  }

  // ---- expT B-frags from trans: element exp(trans[k][16ct+q]) ----
  Frags6 B;
#pragma unroll
  for (int ct = 0; ct < 3; ++ct) {
    const int j = 16 * ct + q;
#pragma unroll
    for (int i = 0; i < 8; ++i) {
      const int k0 = 8 * h + i;
      B.b[0][ct][i] = rne_bf(__expf(trans[k0 * T_DIM + j]));
      const int k1 = 32 + 8 * h + i;
      B.b[1][ct][i] = (k1 < T_DIM) ? rne_bf(__expf(trans[k1 * T_DIM + j])) : (short)0;
    }
  }

  // ---- phase 2: chain.  factors s = s0+t for t in [tstart, 16) ----
  __shared__ short Ml[48 * 64];
  zero_lds(Ml, l);  // k>=48 swizzle slots must stay 0
  const int tstart = (c == 0) ? 1 : 0;  // s=0 is u0, not a factor

  f32x4 C[3][3];
#pragma unroll
  for (int t = 0; t < 16; ++t) {
    if (t < tstart) continue;  // wave-uniform (c is uniform)
    // e-values for this step from em regs: source lane 16*(t>>2)+q holds
    // em[s0+t][{q,16+q,32+q}] in E[0..2][t&3]  (t compile-time after unroll)
    const int src = 16 * (t >> 2) + q;
    const float e0 = __expf(__shfl(E[0][t & 3], src, 64));
    const float e1 = __expf(__shfl(E[1][t & 3], src, 64));
    const float e2 = __expf(__shfl(E[2][t & 3], src, 64));
    matstep(Ml, t == tstart, h, q, B, C);
#pragma unroll
    for (int rt = 0; rt < 3; ++rt)
#pragma unroll
      for (int r = 0; r < 4; ++r) {
        C[rt][0][r] *= e0; C[rt][1][r] *= e1; C[rt][2][r] *= e2;
      }
    if (t < 15) writeM(Ml, h, q, C);
  }
  int ex = store_node(nodes1 + (size_t)(b * 32 + c) * 2304, h, q, C);
  if (l == 0) exp1[b * 32 + c] = ex;
}

// ---------------------------------------------------------------------------
// K2: final — merge 32 nodes (4 waves x 8 serial, RESCALE at wave boundary,
// then wave0 folds 3 partners), log_Z, gold path score, nll atomicAdd.
// 128 blocks x 256 thr.  (unchanged from round 6)
// ---------------------------------------------------------------------------
__global__ __launch_bounds__(256) void k_final(
    const short* __restrict__ nodes1, const int* __restrict__ exp1,
    const float* __restrict__ em, const float* __restrict__ trans,
    const int* __restrict__ tags, float* __restrict__ out) {
  const int b = blockIdx.x, tid = threadIdx.x;
  const int v = tid >> 6, l = tid & 63, h = l >> 4, q = l & 15;
  __shared__ short Ml[4][48 * 64];
  __shared__ short Pc[3][2304];
  __shared__ float gred[4];
  __shared__ int wexp[4];

  // gold path score (all 256 threads)
  float g = 0.f;
  for (int s = tid; s < S_DIM; s += 256) {
    const int tg = tags[s * B_DIM + b];
    g += em[(size_t)(s * B_DIM + b) * T_DIM + tg];
    if (s < S_DIM - 1) g += trans[tg * T_DIM + tags[(s + 1) * B_DIM + b]];
  }
#pragma unroll
  for (int off = 1; off < 64; off <<= 1) g += __shfl_xor(g, off, 64);
  if (l == 0) gred[v] = g;

  // wave v: Q_v = N_{8v} ... N_{8v+7}
  zero_lds(Ml[v], l);
  const short* base = nodes1 + (size_t)(b * 32 + 8 * v) * 2304;
  Frags6 B, Bn;
  load_child(base, h, q, B);
  f32x4 C[3][3];
  for (int t = 0; t < 8; ++t) {
    if (t < 7) load_child(base + (size_t)(t + 1) * 2304, h, q, Bn);
    matstep(Ml[v], t == 0, h, q, B, C);
    if (t < 7) { writeM(Ml[v], h, q, C); B = Bn; }
  }
  // rescale Q_v to max in [0.5,1) — prevents fp32 overflow in the fold
  int ex = rescaleC(C);
  if (l == 0) wexp[v] = ex;
  if (v > 0) storecol(Pc[v - 1], h, q, C);
  else       writeM(Ml[0], h, q, C);
  __syncthreads();

  if (v == 0) {
    // P = Q0 * Q1 * Q2 * Q3  (all rescaled; worst-case growth <= 48^3)
    for (int t = 0; t < 3; ++t) {
      load_child(Pc[t], h, q, B);
      matstep(Ml[0], false, h, q, B, C);
      if (t < 2) writeM(Ml[0], h, q, C);
    }
    // Z = sum_i exp(em[0,b,i]) * rowsum_i(P)
    float Zp = 0.f;
#pragma unroll
    for (int rt = 0; rt < 3; ++rt)
#pragma unroll
      for (int r = 0; r < 4; ++r) {
        float rs = C[rt][0][r] + C[rt][1][r] + C[rt][2][r];
        rs += __shfl_xor(rs, 1, 64); rs += __shfl_xor(rs, 2, 64);
        rs += __shfl_xor(rs, 4, 64); rs += __shfl_xor(rs, 8, 64);
        const int row = 16 * rt + 4 * h + r;
        Zp = fmaf(__expf(em[(size_t)b * T_DIM + row]), rs, Zp);
      }
    Zp += __shfl_xor(Zp, 16, 64); Zp += __shfl_xor(Zp, 32, 64);
    int E = (l < 32) ? exp1[b * 32 + l] : 0;
#pragma unroll
    for (int off = 1; off < 32; off <<= 1) E += __shfl_xor(E, off, 64);
    E += wexp[0] + wexp[1] + wexp[2] + wexp[3];
    const float logZ = __logf(Zp) + (float)E * 0.69314718055994531f;
    const float gold = gred[0] + gred[1] + gred[2] + gred[3];
    if (l == 0) atomicAdd(out, (logZ - gold) * (1.0f / (float)B_DIM));
  }
}

// ---------------------------------------------------------------------------
extern "C" void kernel_launch(void* const* d_in, const int* in_sizes, int n_in,
                              void* d_out, int out_size, void* d_ws, size_t ws_size,
                              hipStream_t stream) {
  const float* wf    = (const float*)d_in[0];
  const float* W     = (const float*)d_in[1];
  const float* bias  = (const float*)d_in[2];
  const float* trans = (const float*)d_in[3];
  const int*   tags  = (const int*)d_in[4];
  float* out = (float*)d_out;

  char* p = (char*)d_ws;
  float* em     = (float*)p;  p += (size_t)S_DIM * B_DIM * T_DIM * 4;  // 12.6 MB
  short* nodes1 = (short*)p;  p += (size_t)128 * 32 * 2304 * 2;        // 18.9 MB
  int*   exp1   = (int*)p;

  k_fused<<<128 * 32, 64, 0, stream>>>(wf, W, bias, trans, em, nodes1, exp1, out);
  k_final<<<128, 256, 0, stream>>>(nodes1, exp1, em, trans, tags, out);
}